// Round 1
// baseline (334.786 us; speedup 1.0000x reference)
//
#include <hip/hip_runtime.h>
#include <math.h>

// Problem constants (from reference)
#define M_ROWS   349184
#define C_CH     80
#define NPOS     2048
#define ALPHA    0.25f
#define GAMMA_P  2.0f
#define SIG_CLMP 1.0e-4f
#define REG_W    2.0f

// d_ws accumulator layout: [0]=neg_sum, [1]=giou_sum, [2]=w_sum, [3]=pos_sum

__device__ __forceinline__ float clamped_sigmoid(float x) {
    float p = 1.0f / (1.0f + __expf(-x));
    return fminf(fmaxf(p, SIG_CLMP), 1.0f - SIG_CLMP);
}

__global__ __launch_bounds__(256) void centernet_loss_main(
    const float* __restrict__ logits,
    const float* __restrict__ hms,
    const float* __restrict__ reg_pred,
    const float* __restrict__ reg_tgt,
    const int*   __restrict__ pos_inds,
    const int*   __restrict__ labels,
    float* __restrict__ acc)
{
    const int tid      = blockIdx.x * blockDim.x + threadIdx.x;
    const int nthreads = gridDim.x * blockDim.x;

    float neg = 0.0f, giou = 0.0f, wsum = 0.0f, pos = 0.0f;

    // ---- negative focal loss over all M*C elements (float4 vectorized) ----
    const int n4 = (M_ROWS * C_CH) / 4;   // 27,934,720 / 4 = 6,983,680
    const float4* lg4 = (const float4*)logits;
    const float4* hm4 = (const float4*)hms;
    for (int i = tid; i < n4; i += nthreads) {
        float4 x = lg4[i];
        float4 h = hm4[i];
        {
            float p = clamped_sigmoid(x.x);
            float q = 1.0f - h.x; float q2 = q * q;
            neg += __logf(1.0f - p) * p * p * (q2 * q2);
        }
        {
            float p = clamped_sigmoid(x.y);
            float q = 1.0f - h.y; float q2 = q * q;
            neg += __logf(1.0f - p) * p * p * (q2 * q2);
        }
        {
            float p = clamped_sigmoid(x.z);
            float q = 1.0f - h.z; float q2 = q * q;
            neg += __logf(1.0f - p) * p * p * (q2 * q2);
        }
        {
            float p = clamped_sigmoid(x.w);
            float q = 1.0f - h.w; float q2 = q * q;
            neg += __logf(1.0f - p) * p * p * (q2 * q2);
        }
    }

    // ---- GIoU regression loss over M rows (one float4 row each) ----
    const float4* rp4 = (const float4*)reg_pred;
    const float4* rt4 = (const float4*)reg_tgt;
    for (int r = tid; r < M_ROWS; r += nthreads) {
        float4 t = rt4[r];
        float mx = fmaxf(fmaxf(t.x, t.y), fmaxf(t.z, t.w));
        if (mx >= 0.0f) {           // invalid rows contribute 0 (w=0)
            float4 p = rp4[r];
            // pl=p.x pt=p.y pr=p.z pb=p.w ; tl=t.x tt=t.y tr=t.z tb=t.w
            float target_area = (t.x + t.z) * (t.y + t.w);
            float pred_area   = (p.x + p.z) * (p.y + p.w);
            float w_int = fminf(p.x, t.x) + fminf(p.z, t.z);
            float h_int = fminf(p.w, t.w) + fminf(p.y, t.y);
            float g_w   = fmaxf(p.x, t.x) + fmaxf(p.z, t.z);
            float g_h   = fmaxf(p.w, t.w) + fmaxf(p.y, t.y);
            float ac    = g_w * g_h;
            float ai    = w_int * h_int;
            float au    = target_area + pred_area - ai;
            float ious  = (ai + 1.0f) / (au + 1.0f);
            float gious = ious - (ac - au) / (ac + 1e-7f);
            giou += 1.0f - gious;
            wsum += 1.0f;
        }
    }

    // ---- positive focal loss: 2048-element gather ----
    for (int i = tid; i < NPOS; i += nthreads) {
        int idx = pos_inds[i] * C_CH + labels[i];
        float p  = clamped_sigmoid(logits[idx]);
        float om = 1.0f - p;
        pos += __logf(p) * om * om;
    }

    // ---- block reduction of 4 partials ----
    const int lane = threadIdx.x & 63;
    const int wave = threadIdx.x >> 6;
    #pragma unroll
    for (int off = 32; off > 0; off >>= 1) {
        neg  += __shfl_down(neg,  off);
        giou += __shfl_down(giou, off);
        wsum += __shfl_down(wsum, off);
        pos  += __shfl_down(pos,  off);
    }
    __shared__ float smem[4][4];
    if (lane == 0) {
        smem[wave][0] = neg;  smem[wave][1] = giou;
        smem[wave][2] = wsum; smem[wave][3] = pos;
    }
    __syncthreads();
    if (threadIdx.x == 0) {
        float a = 0, b = 0, c = 0, d = 0;
        #pragma unroll
        for (int w = 0; w < 4; ++w) {
            a += smem[w][0]; b += smem[w][1];
            c += smem[w][2]; d += smem[w][3];
        }
        atomicAdd(&acc[0], a);
        atomicAdd(&acc[1], b);
        atomicAdd(&acc[2], c);
        atomicAdd(&acc[3], d);
    }
}

__global__ void centernet_loss_finalize(const float* __restrict__ acc,
                                        float* __restrict__ out)
{
    if (threadIdx.x == 0 && blockIdx.x == 0) {
        float neg_sum  = acc[0];
        float giou_sum = acc[1];
        float w_sum    = acc[2];
        float pos_sum  = acc[3];
        const float inv_npos = 1.0f / (float)NPOS;
        out[0] = -ALPHA * pos_sum * inv_npos;                 // pos_loss (POS_W=1)
        out[1] = -(1.0f - ALPHA) * neg_sum * inv_npos;        // neg_loss (NEG_W=1)
        out[2] = REG_W * giou_sum / fmaxf(w_sum, 1.0f);       // reg_loss
    }
}

extern "C" void kernel_launch(void* const* d_in, const int* in_sizes, int n_in,
                              void* d_out, int out_size, void* d_ws, size_t ws_size,
                              hipStream_t stream) {
    const float* logits   = (const float*)d_in[0];
    const float* hms      = (const float*)d_in[1];
    const float* reg_pred = (const float*)d_in[2];
    const float* reg_tgt  = (const float*)d_in[3];
    const int*   pos_inds = (const int*)d_in[4];
    const int*   labels   = (const int*)d_in[5];
    float* out = (float*)d_out;
    float* acc = (float*)d_ws;

    hipMemsetAsync(acc, 0, 4 * sizeof(float), stream);
    centernet_loss_main<<<2048, 256, 0, stream>>>(
        logits, hms, reg_pred, reg_tgt, pos_inds, labels, acc);
    centernet_loss_finalize<<<1, 64, 0, stream>>>(acc, out);
}

// Round 2
// 259.011 us; speedup vs baseline: 1.2926x; 1.2926x over previous
//
#include <hip/hip_runtime.h>
#include <math.h>

#define M_ROWS   349184
#define C_CH     80
#define NPOS     2048
#define ALPHA    0.25f
#define SIG_CLMP 1.0e-4f
#define REG_W    2.0f

#define NBLOCKS  2048
#define NTHREADS 256

__device__ __forceinline__ float clamped_sigmoid(float x) {
    float p = 1.0f / (1.0f + __expf(-x));
    return fminf(fmaxf(p, SIG_CLMP), 1.0f - SIG_CLMP);
}

__device__ __forceinline__ float neg_term(float x, float h) {
    float p = clamped_sigmoid(x);
    float q = 1.0f - h;
    float q2 = q * q;
    return __logf(1.0f - p) * p * p * (q2 * q2);
}

__device__ __forceinline__ float neg_term4(float4 x, float4 h) {
    return neg_term(x.x, h.x) + neg_term(x.y, h.y) +
           neg_term(x.z, h.z) + neg_term(x.w, h.w);
}

// partials layout: float4 per block {neg, giou, wsum, pos}
__global__ __launch_bounds__(NTHREADS) void centernet_loss_main(
    const float* __restrict__ logits,
    const float* __restrict__ hms,
    const float* __restrict__ reg_pred,
    const float* __restrict__ reg_tgt,
    const int*   __restrict__ pos_inds,
    const int*   __restrict__ labels,
    float4* __restrict__ partials)
{
    const int tid      = blockIdx.x * blockDim.x + threadIdx.x;
    const int nthreads = NBLOCKS * NTHREADS;   // 524288

    float neg = 0.0f, giou = 0.0f, wsum = 0.0f, pos = 0.0f;

    const int n4 = (M_ROWS * C_CH) / 4;        // 6,983,680
    const float4* lg4 = (const float4*)logits;
    const float4* hm4 = (const float4*)hms;

    // ---- negative focal loss: 4x unrolled, loads hoisted for MLP ----
    int i = tid;
    for (; i + 3 * nthreads < n4; i += 4 * nthreads) {
        // issue all 8 loads before consuming any
        float4 x0 = lg4[i];
        float4 x1 = lg4[i + nthreads];
        float4 x2 = lg4[i + 2 * nthreads];
        float4 x3 = lg4[i + 3 * nthreads];
        float4 h0 = hm4[i];
        float4 h1 = hm4[i + nthreads];
        float4 h2 = hm4[i + 2 * nthreads];
        float4 h3 = hm4[i + 3 * nthreads];
        neg += neg_term4(x0, h0);
        neg += neg_term4(x1, h1);
        neg += neg_term4(x2, h2);
        neg += neg_term4(x3, h3);
    }
    for (; i < n4; i += nthreads) {
        neg += neg_term4(lg4[i], hm4[i]);
    }

    // ---- GIoU regression loss (each thread: 0 or 1 rows) ----
    const float4* rp4 = (const float4*)reg_pred;
    const float4* rt4 = (const float4*)reg_tgt;
    for (int r = tid; r < M_ROWS; r += nthreads) {
        float4 t = rt4[r];
        float mx = fmaxf(fmaxf(t.x, t.y), fmaxf(t.z, t.w));
        if (mx >= 0.0f) {
            float4 p = rp4[r];
            float target_area = (t.x + t.z) * (t.y + t.w);
            float pred_area   = (p.x + p.z) * (p.y + p.w);
            float w_int = fminf(p.x, t.x) + fminf(p.z, t.z);
            float h_int = fminf(p.w, t.w) + fminf(p.y, t.y);
            float g_w   = fmaxf(p.x, t.x) + fmaxf(p.z, t.z);
            float g_h   = fmaxf(p.w, t.w) + fmaxf(p.y, t.y);
            float ac    = g_w * g_h;
            float ai    = w_int * h_int;
            float au    = target_area + pred_area - ai;
            float ious  = (ai + 1.0f) / (au + 1.0f);
            float gious = ious - (ac - au) / (ac + 1e-7f);
            giou += 1.0f - gious;
            wsum += 1.0f;
        }
    }

    // ---- positive focal loss gather (first 2048 threads) ----
    for (int k = tid; k < NPOS; k += nthreads) {
        int idx = pos_inds[k] * C_CH + labels[k];
        float p  = clamped_sigmoid(logits[idx]);
        float om = 1.0f - p;
        pos += __logf(p) * om * om;
    }

    // ---- block reduction, one float4 store per block ----
    const int lane = threadIdx.x & 63;
    const int wave = threadIdx.x >> 6;
    #pragma unroll
    for (int off = 32; off > 0; off >>= 1) {
        neg  += __shfl_down(neg,  off);
        giou += __shfl_down(giou, off);
        wsum += __shfl_down(wsum, off);
        pos  += __shfl_down(pos,  off);
    }
    __shared__ float smem[4][4];
    if (lane == 0) {
        smem[wave][0] = neg;  smem[wave][1] = giou;
        smem[wave][2] = wsum; smem[wave][3] = pos;
    }
    __syncthreads();
    if (threadIdx.x == 0) {
        float4 v;
        v.x = smem[0][0] + smem[1][0] + smem[2][0] + smem[3][0];
        v.y = smem[0][1] + smem[1][1] + smem[2][1] + smem[3][1];
        v.z = smem[0][2] + smem[1][2] + smem[2][2] + smem[3][2];
        v.w = smem[0][3] + smem[1][3] + smem[2][3] + smem[3][3];
        partials[blockIdx.x] = v;
    }
}

// single block: reduce 2048 partials + final scaling
__global__ __launch_bounds__(256) void centernet_loss_reduce(
    const float4* __restrict__ partials,
    float* __restrict__ out)
{
    float neg = 0.0f, giou = 0.0f, wsum = 0.0f, pos = 0.0f;
    for (int i = threadIdx.x; i < NBLOCKS; i += 256) {
        float4 v = partials[i];
        neg += v.x; giou += v.y; wsum += v.z; pos += v.w;
    }
    const int lane = threadIdx.x & 63;
    const int wave = threadIdx.x >> 6;
    #pragma unroll
    for (int off = 32; off > 0; off >>= 1) {
        neg  += __shfl_down(neg,  off);
        giou += __shfl_down(giou, off);
        wsum += __shfl_down(wsum, off);
        pos  += __shfl_down(pos,  off);
    }
    __shared__ float smem[4][4];
    if (lane == 0) {
        smem[wave][0] = neg;  smem[wave][1] = giou;
        smem[wave][2] = wsum; smem[wave][3] = pos;
    }
    __syncthreads();
    if (threadIdx.x == 0) {
        float n = smem[0][0] + smem[1][0] + smem[2][0] + smem[3][0];
        float g = smem[0][1] + smem[1][1] + smem[2][1] + smem[3][1];
        float w = smem[0][2] + smem[1][2] + smem[2][2] + smem[3][2];
        float p = smem[0][3] + smem[1][3] + smem[2][3] + smem[3][3];
        const float inv_npos = 1.0f / (float)NPOS;
        out[0] = -ALPHA * p * inv_npos;
        out[1] = -(1.0f - ALPHA) * n * inv_npos;
        out[2] = REG_W * g / fmaxf(w, 1.0f);
    }
}

extern "C" void kernel_launch(void* const* d_in, const int* in_sizes, int n_in,
                              void* d_out, int out_size, void* d_ws, size_t ws_size,
                              hipStream_t stream) {
    const float* logits   = (const float*)d_in[0];
    const float* hms      = (const float*)d_in[1];
    const float* reg_pred = (const float*)d_in[2];
    const float* reg_tgt  = (const float*)d_in[3];
    const int*   pos_inds = (const int*)d_in[4];
    const int*   labels   = (const int*)d_in[5];
    float* out = (float*)d_out;
    float4* partials = (float4*)d_ws;   // 2048 * 16 B = 32 KB

    centernet_loss_main<<<NBLOCKS, NTHREADS, 0, stream>>>(
        logits, hms, reg_pred, reg_tgt, pos_inds, labels, partials);
    centernet_loss_reduce<<<1, 256, 0, stream>>>(partials, out);
}

// Round 3
// 256.374 us; speedup vs baseline: 1.3059x; 1.0103x over previous
//
#include <hip/hip_runtime.h>
#include <math.h>

#define M_ROWS   349184
#define C_CH     80
#define NPOS     2048
#define ALPHA    0.25f
#define SIG_CLMP 1.0e-4f
#define REG_W    2.0f

#define NBLOCKS  2048
#define NTHREADS 256
// n4 = M*C/4 = 6,983,680 = 2048 * 3410 exactly
#define N4       6983680
#define CHUNK    3410

__device__ __forceinline__ float fast_rcp(float x) {
    return __builtin_amdgcn_rcpf(x);
}

__device__ __forceinline__ float clamped_sigmoid(float x) {
    float e = __expf(-x);
    float p = fast_rcp(1.0f + e);
    return fminf(fmaxf(p, SIG_CLMP), 1.0f - SIG_CLMP);
}

__device__ __forceinline__ float neg_term(float x, float h) {
    float p = clamped_sigmoid(x);
    float q = 1.0f - h;
    float q2 = q * q;
    return __logf(1.0f - p) * (p * p) * (q2 * q2);
}

__device__ __forceinline__ float neg_term4(float4 x, float4 h) {
    return neg_term(x.x, h.x) + neg_term(x.y, h.y) +
           neg_term(x.z, h.z) + neg_term(x.w, h.w);
}

// partials: one float4 {neg, giou, wsum, pos} per block
__global__ __launch_bounds__(NTHREADS) void centernet_loss_main(
    const float* __restrict__ logits,
    const float* __restrict__ hms,
    const float* __restrict__ reg_pred,
    const float* __restrict__ reg_tgt,
    const int*   __restrict__ pos_inds,
    const int*   __restrict__ labels,
    float4* __restrict__ partials)
{
    const int t   = threadIdx.x;
    const int tid = blockIdx.x * NTHREADS + t;

    float neg = 0.0f, giou = 0.0f, wsum = 0.0f, pos = 0.0f;

    const float4* lg4 = (const float4*)logits;
    const float4* hm4 = (const float4*)hms;

    // ---- negative focal loss: contiguous per-block chunk ----
    // Block b owns [b*CHUNK, (b+1)*CHUNK). All 8 concurrent loads of a pass
    // fall in one 16 KB window per array -> stable pages, good L2/DRAM locality.
    const int start = blockIdx.x * CHUNK;
    const int end   = start + CHUNK;

    int i = start + t;
    // 4x unrolled: 12 * 256 = 3072 of 3410 per block
    for (; i + 3 * NTHREADS < end; i += 4 * NTHREADS) {
        float4 x0 = lg4[i];
        float4 x1 = lg4[i + NTHREADS];
        float4 x2 = lg4[i + 2 * NTHREADS];
        float4 x3 = lg4[i + 3 * NTHREADS];
        float4 h0 = hm4[i];
        float4 h1 = hm4[i + NTHREADS];
        float4 h2 = hm4[i + 2 * NTHREADS];
        float4 h3 = hm4[i + 3 * NTHREADS];
        neg += neg_term4(x0, h0);
        neg += neg_term4(x1, h1);
        neg += neg_term4(x2, h2);
        neg += neg_term4(x3, h3);
    }
    // tail (338 elements per block)
    for (; i < end; i += NTHREADS) {
        neg += neg_term4(lg4[i], hm4[i]);
    }

    // ---- GIoU regression loss: contiguous per-block chunk of rows ----
    // M_ROWS = 349184 = 2048 * 170.5 -> use 171 rows/block upper bound
    const int rstart = blockIdx.x * 171;
    const int rend   = min(rstart + 171, M_ROWS);
    const float4* rp4 = (const float4*)reg_pred;
    const float4* rt4 = (const float4*)reg_tgt;
    for (int r = rstart + t; r < rend; r += NTHREADS) {
        float4 tt = rt4[r];
        float mx = fmaxf(fmaxf(tt.x, tt.y), fmaxf(tt.z, tt.w));
        if (mx >= 0.0f) {
            float4 p = rp4[r];
            float target_area = (tt.x + tt.z) * (tt.y + tt.w);
            float pred_area   = (p.x + p.z) * (p.y + p.w);
            float w_int = fminf(p.x, tt.x) + fminf(p.z, tt.z);
            float h_int = fminf(p.w, tt.w) + fminf(p.y, tt.y);
            float g_w   = fmaxf(p.x, tt.x) + fmaxf(p.z, tt.z);
            float g_h   = fmaxf(p.w, tt.w) + fmaxf(p.y, tt.y);
            float ac    = g_w * g_h;
            float ai    = w_int * h_int;
            float au    = target_area + pred_area - ai;
            float ious  = (ai + 1.0f) * fast_rcp(au + 1.0f);
            float gious = ious - (ac - au) * fast_rcp(ac + 1e-7f);
            giou += 1.0f - gious;
            wsum += 1.0f;
        }
    }

    // ---- positive focal loss gather: 1 element per block ----
    if (t == 0 && blockIdx.x < NPOS) {
        int k = blockIdx.x;
        int idx = pos_inds[k] * C_CH + labels[k];
        float p  = clamped_sigmoid(logits[idx]);
        float om = 1.0f - p;
        pos = __logf(p) * om * om;
    }

    // ---- block reduction, one float4 store per block ----
    const int lane = t & 63;
    const int wave = t >> 6;
    #pragma unroll
    for (int off = 32; off > 0; off >>= 1) {
        neg  += __shfl_down(neg,  off);
        giou += __shfl_down(giou, off);
        wsum += __shfl_down(wsum, off);
        pos  += __shfl_down(pos,  off);
    }
    __shared__ float smem[4][4];
    if (lane == 0) {
        smem[wave][0] = neg;  smem[wave][1] = giou;
        smem[wave][2] = wsum; smem[wave][3] = pos;
    }
    __syncthreads();
    if (t == 0) {
        float4 v;
        v.x = smem[0][0] + smem[1][0] + smem[2][0] + smem[3][0];
        v.y = smem[0][1] + smem[1][1] + smem[2][1] + smem[3][1];
        v.z = smem[0][2] + smem[1][2] + smem[2][2] + smem[3][2];
        // pos: wave-0 shuffle already summed; only t==0 contributed, value
        // travels via smem[0][3]; other waves contribute 0.
        v.w = smem[0][3] + smem[1][3] + smem[2][3] + smem[3][3];
        partials[blockIdx.x] = v;
    }
}

// single block: reduce 2048 partials + final scaling
__global__ __launch_bounds__(256) void centernet_loss_reduce(
    const float4* __restrict__ partials,
    float* __restrict__ out)
{
    float neg = 0.0f, giou = 0.0f, wsum = 0.0f, pos = 0.0f;
    for (int i = threadIdx.x; i < NBLOCKS; i += 256) {
        float4 v = partials[i];
        neg += v.x; giou += v.y; wsum += v.z; pos += v.w;
    }
    const int lane = threadIdx.x & 63;
    const int wave = threadIdx.x >> 6;
    #pragma unroll
    for (int off = 32; off > 0; off >>= 1) {
        neg  += __shfl_down(neg,  off);
        giou += __shfl_down(giou, off);
        wsum += __shfl_down(wsum, off);
        pos  += __shfl_down(pos,  off);
    }
    __shared__ float smem[4][4];
    if (lane == 0) {
        smem[wave][0] = neg;  smem[wave][1] = giou;
        smem[wave][2] = wsum; smem[wave][3] = pos;
    }
    __syncthreads();
    if (threadIdx.x == 0) {
        float n = smem[0][0] + smem[1][0] + smem[2][0] + smem[3][0];
        float g = smem[0][1] + smem[1][1] + smem[2][1] + smem[3][1];
        float w = smem[0][2] + smem[1][2] + smem[2][2] + smem[3][2];
        float p = smem[0][3] + smem[1][3] + smem[2][3] + smem[3][3];
        const float inv_npos = 1.0f / (float)NPOS;
        out[0] = -ALPHA * p * inv_npos;
        out[1] = -(1.0f - ALPHA) * n * inv_npos;
        out[2] = REG_W * g / fmaxf(w, 1.0f);
    }
}

extern "C" void kernel_launch(void* const* d_in, const int* in_sizes, int n_in,
                              void* d_out, int out_size, void* d_ws, size_t ws_size,
                              hipStream_t stream) {
    const float* logits   = (const float*)d_in[0];
    const float* hms      = (const float*)d_in[1];
    const float* reg_pred = (const float*)d_in[2];
    const float* reg_tgt  = (const float*)d_in[3];
    const int*   pos_inds = (const int*)d_in[4];
    const int*   labels   = (const int*)d_in[5];
    float* out = (float*)d_out;
    float4* partials = (float4*)d_ws;   // 2048 * 16 B = 32 KB

    centernet_loss_main<<<NBLOCKS, NTHREADS, 0, stream>>>(
        logits, hms, reg_pred, reg_tgt, pos_inds, labels, partials);
    centernet_loss_reduce<<<1, 256, 0, stream>>>(partials, out);
}

// Round 5
// 234.452 us; speedup vs baseline: 1.4280x; 1.0935x over previous
//
#include <hip/hip_runtime.h>
#include <math.h>

#define M_ROWS   349184
#define C_CH     80
#define NPOS     2048
#define ALPHA    0.25f
#define SIG_CLMP 1.0e-4f
#define REG_W    2.0f

#define NBLOCKS  512
#define NTHREADS 1024
// n4 = M*C/4 = 6,983,680 = 512 * 13640 exactly
#define N4       6983680
#define CHUNK4   13640
// M_ROWS = 512 * 682 exactly
#define ROWS_PB  682
// NPOS = 512 * 4
#define POS_PB   4

// native vector type (HIP_vector_type is not accepted by nontemporal builtins)
typedef float vf4 __attribute__((ext_vector_type(4)));

__device__ __forceinline__ float fast_rcp(float x) {
    return __builtin_amdgcn_rcpf(x);
}

__device__ __forceinline__ float clamped_sigmoid(float x) {
    float p = fast_rcp(1.0f + __expf(-x));
    return fminf(fmaxf(p, SIG_CLMP), 1.0f - SIG_CLMP);
}

__device__ __forceinline__ float neg_term(float x, float h) {
    float p = clamped_sigmoid(x);
    float q = 1.0f - h;
    float q2 = q * q;
    return __logf(1.0f - p) * (p * p) * (q2 * q2);
}

__device__ __forceinline__ float neg_term4(vf4 x, vf4 h) {
    return neg_term(x.x, h.x) + neg_term(x.y, h.y) +
           neg_term(x.z, h.z) + neg_term(x.w, h.w);
}

__device__ __forceinline__ vf4 ldnt4(const vf4* p) {
    return __builtin_nontemporal_load(p);
}

// partials: one float4 {neg, giou, wsum, pos} per block
__global__ __launch_bounds__(NTHREADS) void centernet_loss_main(
    const float* __restrict__ logits,
    const float* __restrict__ hms,
    const float* __restrict__ reg_pred,
    const float* __restrict__ reg_tgt,
    const int*   __restrict__ pos_inds,
    const int*   __restrict__ labels,
    float4* __restrict__ partials)
{
    const int t = threadIdx.x;
    // CU-adjacency swizzle: blocks b and b+256 share a CU (round-robin
    // dispatch over 256 CUs); give them adjacent chunks so each CU streams
    // one contiguous region per array.
    const int b = ((int)blockIdx.x & 255) * 2 + ((int)blockIdx.x >> 8);

    float neg = 0.0f, giou = 0.0f, wsum = 0.0f, pos = 0.0f;

    const vf4* lg4 = (const vf4*)logits;
    const vf4* hm4 = (const vf4*)hms;

    // ---- negative focal loss: contiguous per-block chunk, 4x unroll ----
    const int start = b * CHUNK4;
    const int end   = start + CHUNK4;

    int i = start + t;
    // 3 unrolled iterations: 3 * 4096 = 12288 of 13640
    for (; i + 3 * NTHREADS < end; i += 4 * NTHREADS) {
        vf4 x0 = ldnt4(&lg4[i]);
        vf4 x1 = ldnt4(&lg4[i + NTHREADS]);
        vf4 x2 = ldnt4(&lg4[i + 2 * NTHREADS]);
        vf4 x3 = ldnt4(&lg4[i + 3 * NTHREADS]);
        vf4 h0 = ldnt4(&hm4[i]);
        vf4 h1 = ldnt4(&hm4[i + NTHREADS]);
        vf4 h2 = ldnt4(&hm4[i + 2 * NTHREADS]);
        vf4 h3 = ldnt4(&hm4[i + 3 * NTHREADS]);
        neg += neg_term4(x0, h0);
        neg += neg_term4(x1, h1);
        neg += neg_term4(x2, h2);
        neg += neg_term4(x3, h3);
    }
    // tail (1352 float4 per block)
    for (; i < end; i += NTHREADS) {
        neg += neg_term4(ldnt4(&lg4[i]), ldnt4(&hm4[i]));
    }

    // ---- GIoU regression loss: contiguous per-block rows ----
    const int rstart = b * ROWS_PB;
    const vf4* rp4 = (const vf4*)reg_pred;
    const vf4* rt4 = (const vf4*)reg_tgt;
    for (int r = rstart + t; r < rstart + ROWS_PB; r += NTHREADS) {
        vf4 tt = rt4[r];
        float mx = fmaxf(fmaxf(tt.x, tt.y), fmaxf(tt.z, tt.w));
        if (mx >= 0.0f) {
            vf4 p = rp4[r];
            float target_area = (tt.x + tt.z) * (tt.y + tt.w);
            float pred_area   = (p.x + p.z) * (p.y + p.w);
            float w_int = fminf(p.x, tt.x) + fminf(p.z, tt.z);
            float h_int = fminf(p.w, tt.w) + fminf(p.y, tt.y);
            float g_w   = fmaxf(p.x, tt.x) + fmaxf(p.z, tt.z);
            float g_h   = fmaxf(p.w, tt.w) + fmaxf(p.y, tt.y);
            float ac    = g_w * g_h;
            float ai    = w_int * h_int;
            float au    = target_area + pred_area - ai;
            float ious  = (ai + 1.0f) * fast_rcp(au + 1.0f);
            float gious = ious - (ac - au) * fast_rcp(ac + 1e-7f);
            giou += 1.0f - gious;
            wsum += 1.0f;
        }
    }

    // ---- positive focal loss gather: 4 per block ----
    if (t < POS_PB) {
        int k = b * POS_PB + t;
        int idx = pos_inds[k] * C_CH + labels[k];
        float p  = clamped_sigmoid(logits[idx]);
        float om = 1.0f - p;
        pos = __logf(p) * om * om;
    }

    // ---- block reduction (16 waves), one float4 store per block ----
    const int lane = t & 63;
    const int wave = t >> 6;
    #pragma unroll
    for (int off = 32; off > 0; off >>= 1) {
        neg  += __shfl_down(neg,  off);
        giou += __shfl_down(giou, off);
        wsum += __shfl_down(wsum, off);
        pos  += __shfl_down(pos,  off);
    }
    __shared__ float smem[16][4];
    if (lane == 0) {
        smem[wave][0] = neg;  smem[wave][1] = giou;
        smem[wave][2] = wsum; smem[wave][3] = pos;
    }
    __syncthreads();
    if (t == 0) {
        float4 v = make_float4(0.f, 0.f, 0.f, 0.f);
        #pragma unroll
        for (int w = 0; w < 16; ++w) {
            v.x += smem[w][0]; v.y += smem[w][1];
            v.z += smem[w][2]; v.w += smem[w][3];
        }
        partials[blockIdx.x] = v;
    }
}

// single block: reduce 512 partials + final scaling
__global__ __launch_bounds__(256) void centernet_loss_reduce(
    const float4* __restrict__ partials,
    float* __restrict__ out)
{
    float neg = 0.0f, giou = 0.0f, wsum = 0.0f, pos = 0.0f;
    for (int i = threadIdx.x; i < NBLOCKS; i += 256) {
        float4 v = partials[i];
        neg += v.x; giou += v.y; wsum += v.z; pos += v.w;
    }
    const int lane = threadIdx.x & 63;
    const int wave = threadIdx.x >> 6;
    #pragma unroll
    for (int off = 32; off > 0; off >>= 1) {
        neg  += __shfl_down(neg,  off);
        giou += __shfl_down(giou, off);
        wsum += __shfl_down(wsum, off);
        pos  += __shfl_down(pos,  off);
    }
    __shared__ float smem[4][4];
    if (lane == 0) {
        smem[wave][0] = neg;  smem[wave][1] = giou;
        smem[wave][2] = wsum; smem[wave][3] = pos;
    }
    __syncthreads();
    if (threadIdx.x == 0) {
        float n = smem[0][0] + smem[1][0] + smem[2][0] + smem[3][0];
        float g = smem[0][1] + smem[1][1] + smem[2][1] + smem[3][1];
        float w = smem[0][2] + smem[1][2] + smem[2][2] + smem[3][2];
        float p = smem[0][3] + smem[1][3] + smem[2][3] + smem[3][3];
        const float inv_npos = 1.0f / (float)NPOS;
        out[0] = -ALPHA * p * inv_npos;
        out[1] = -(1.0f - ALPHA) * n * inv_npos;
        out[2] = REG_W * g / fmaxf(w, 1.0f);
    }
}

extern "C" void kernel_launch(void* const* d_in, const int* in_sizes, int n_in,
                              void* d_out, int out_size, void* d_ws, size_t ws_size,
                              hipStream_t stream) {
    const float* logits   = (const float*)d_in[0];
    const float* hms      = (const float*)d_in[1];
    const float* reg_pred = (const float*)d_in[2];
    const float* reg_tgt  = (const float*)d_in[3];
    const int*   pos_inds = (const int*)d_in[4];
    const int*   labels   = (const int*)d_in[5];
    float* out = (float*)d_out;
    float4* partials = (float4*)d_ws;   // 512 * 16 B = 8 KB

    centernet_loss_main<<<NBLOCKS, NTHREADS, 0, stream>>>(
        logits, hms, reg_pred, reg_tgt, pos_inds, labels, partials);
    centernet_loss_reduce<<<1, 256, 0, stream>>>(partials, out);
}

// Round 6
// 234.116 us; speedup vs baseline: 1.4300x; 1.0014x over previous
//
#include <hip/hip_runtime.h>
#include <math.h>

#define M_ROWS   349184
#define C_CH     80
#define NPOS     2048
#define ALPHA    0.25f
#define SIG_CLMP 1.0e-4f
#define REG_W    2.0f

#define NBLOCKS  512
#define NTHREADS 1024
// n4 = M*C/4 = 6,983,680 = 512 * 13640 exactly
#define N4       6983680
#define CHUNK4   13640
// M_ROWS = 512 * 682 exactly
#define ROWS_PB  682
// NPOS = 512 * 4
#define POS_PB   4

// native vector type (HIP_vector_type is not accepted by nontemporal builtins)
typedef float vf4 __attribute__((ext_vector_type(4)));

__device__ __forceinline__ float fast_rcp(float x) {
    return __builtin_amdgcn_rcpf(x);
}

__device__ __forceinline__ float clamped_sigmoid(float x) {
    float p = fast_rcp(1.0f + __expf(-x));
    return fminf(fmaxf(p, SIG_CLMP), 1.0f - SIG_CLMP);
}

__device__ __forceinline__ float neg_term(float x, float h) {
    float p = clamped_sigmoid(x);
    float q = 1.0f - h;
    float q2 = q * q;
    return __logf(1.0f - p) * (p * p) * (q2 * q2);
}

__device__ __forceinline__ float neg_term4(vf4 x, vf4 h) {
    return neg_term(x.x, h.x) + neg_term(x.y, h.y) +
           neg_term(x.z, h.z) + neg_term(x.w, h.w);
}

__device__ __forceinline__ vf4 ldnt4(const vf4* p) {
    return __builtin_nontemporal_load(p);
}

// partials: one float4 {neg, giou, wsum, pos} per block
__global__ __launch_bounds__(NTHREADS) void centernet_loss_main(
    const float* __restrict__ logits,
    const float* __restrict__ hms,
    const float* __restrict__ reg_pred,
    const float* __restrict__ reg_tgt,
    const int*   __restrict__ pos_inds,
    const int*   __restrict__ labels,
    float4* __restrict__ partials)
{
    const int t = threadIdx.x;
    // CU-adjacency swizzle: blocks b and b+256 share a CU (round-robin
    // dispatch over 256 CUs); adjacent chunks stream from one CU.
    const int b = ((int)blockIdx.x & 255) * 2 + ((int)blockIdx.x >> 8);

    float neg = 0.0f, giou = 0.0f, wsum = 0.0f, pos = 0.0f;

    const vf4* lg4 = (const vf4*)logits;
    const vf4* hm4 = (const vf4*)hms;

    // ---- negative focal loss: contiguous per-block chunk, 6x unroll ----
    // 12 loads (48 payload VGPRs) hoisted before any consume -> deep MLP.
    const int start = b * CHUNK4;
    const int end   = start + CHUNK4;

    int i = start + t;
    // 2 full passes: 2 * 6144 = 12288 of 13640
    for (; i + 5 * NTHREADS < end; i += 6 * NTHREADS) {
        vf4 x0 = ldnt4(&lg4[i]);
        vf4 x1 = ldnt4(&lg4[i + NTHREADS]);
        vf4 x2 = ldnt4(&lg4[i + 2 * NTHREADS]);
        vf4 x3 = ldnt4(&lg4[i + 3 * NTHREADS]);
        vf4 x4 = ldnt4(&lg4[i + 4 * NTHREADS]);
        vf4 x5 = ldnt4(&lg4[i + 5 * NTHREADS]);
        vf4 h0 = ldnt4(&hm4[i]);
        vf4 h1 = ldnt4(&hm4[i + NTHREADS]);
        vf4 h2 = ldnt4(&hm4[i + 2 * NTHREADS]);
        vf4 h3 = ldnt4(&hm4[i + 3 * NTHREADS]);
        vf4 h4 = ldnt4(&hm4[i + 4 * NTHREADS]);
        vf4 h5 = ldnt4(&hm4[i + 5 * NTHREADS]);
        neg += neg_term4(x0, h0);
        neg += neg_term4(x1, h1);
        neg += neg_term4(x2, h2);
        neg += neg_term4(x3, h3);
        neg += neg_term4(x4, h4);
        neg += neg_term4(x5, h5);
    }
    // guarded tail: 1352 float4 per block (2 iterations, 2nd partial)
    for (; i < end; i += NTHREADS) {
        neg += neg_term4(ldnt4(&lg4[i]), ldnt4(&hm4[i]));
    }

    // ---- GIoU regression loss: contiguous per-block rows ----
    const int rstart = b * ROWS_PB;
    const vf4* rp4 = (const vf4*)reg_pred;
    const vf4* rt4 = (const vf4*)reg_tgt;
    for (int r = rstart + t; r < rstart + ROWS_PB; r += NTHREADS) {
        vf4 tt = rt4[r];
        float mx = fmaxf(fmaxf(tt.x, tt.y), fmaxf(tt.z, tt.w));
        if (mx >= 0.0f) {
            vf4 p = rp4[r];
            float target_area = (tt.x + tt.z) * (tt.y + tt.w);
            float pred_area   = (p.x + p.z) * (p.y + p.w);
            float w_int = fminf(p.x, tt.x) + fminf(p.z, tt.z);
            float h_int = fminf(p.w, tt.w) + fminf(p.y, tt.y);
            float g_w   = fmaxf(p.x, tt.x) + fmaxf(p.z, tt.z);
            float g_h   = fmaxf(p.w, tt.w) + fmaxf(p.y, tt.y);
            float ac    = g_w * g_h;
            float ai    = w_int * h_int;
            float au    = target_area + pred_area - ai;
            float ious  = (ai + 1.0f) * fast_rcp(au + 1.0f);
            float gious = ious - (ac - au) * fast_rcp(ac + 1e-7f);
            giou += 1.0f - gious;
            wsum += 1.0f;
        }
    }

    // ---- positive focal loss gather: 4 per block ----
    if (t < POS_PB) {
        int k = b * POS_PB + t;
        int idx = pos_inds[k] * C_CH + labels[k];
        float p  = clamped_sigmoid(logits[idx]);
        float om = 1.0f - p;
        pos = __logf(p) * om * om;
    }

    // ---- block reduction (16 waves), one float4 store per block ----
    const int lane = t & 63;
    const int wave = t >> 6;
    #pragma unroll
    for (int off = 32; off > 0; off >>= 1) {
        neg  += __shfl_down(neg,  off);
        giou += __shfl_down(giou, off);
        wsum += __shfl_down(wsum, off);
        pos  += __shfl_down(pos,  off);
    }
    __shared__ float smem[16][4];
    if (lane == 0) {
        smem[wave][0] = neg;  smem[wave][1] = giou;
        smem[wave][2] = wsum; smem[wave][3] = pos;
    }
    __syncthreads();
    if (t == 0) {
        float4 v = make_float4(0.f, 0.f, 0.f, 0.f);
        #pragma unroll
        for (int w = 0; w < 16; ++w) {
            v.x += smem[w][0]; v.y += smem[w][1];
            v.z += smem[w][2]; v.w += smem[w][3];
        }
        partials[blockIdx.x] = v;
    }
}

// single block: reduce 512 partials + final scaling
__global__ __launch_bounds__(256) void centernet_loss_reduce(
    const float4* __restrict__ partials,
    float* __restrict__ out)
{
    float neg = 0.0f, giou = 0.0f, wsum = 0.0f, pos = 0.0f;
    for (int i = threadIdx.x; i < NBLOCKS; i += 256) {
        float4 v = partials[i];
        neg += v.x; giou += v.y; wsum += v.z; pos += v.w;
    }
    const int lane = threadIdx.x & 63;
    const int wave = threadIdx.x >> 6;
    #pragma unroll
    for (int off = 32; off > 0; off >>= 1) {
        neg  += __shfl_down(neg,  off);
        giou += __shfl_down(giou, off);
        wsum += __shfl_down(wsum, off);
        pos  += __shfl_down(pos,  off);
    }
    __shared__ float smem[4][4];
    if (lane == 0) {
        smem[wave][0] = neg;  smem[wave][1] = giou;
        smem[wave][2] = wsum; smem[wave][3] = pos;
    }
    __syncthreads();
    if (threadIdx.x == 0) {
        float n = smem[0][0] + smem[1][0] + smem[2][0] + smem[3][0];
        float g = smem[0][1] + smem[1][1] + smem[2][1] + smem[3][1];
        float w = smem[0][2] + smem[1][2] + smem[2][2] + smem[3][2];
        float p = smem[0][3] + smem[1][3] + smem[2][3] + smem[3][3];
        const float inv_npos = 1.0f / (float)NPOS;
        out[0] = -ALPHA * p * inv_npos;
        out[1] = -(1.0f - ALPHA) * n * inv_npos;
        out[2] = REG_W * g / fmaxf(w, 1.0f);
    }
}

extern "C" void kernel_launch(void* const* d_in, const int* in_sizes, int n_in,
                              void* d_out, int out_size, void* d_ws, size_t ws_size,
                              hipStream_t stream) {
    const float* logits   = (const float*)d_in[0];
    const float* hms      = (const float*)d_in[1];
    const float* reg_pred = (const float*)d_in[2];
    const float* reg_tgt  = (const float*)d_in[3];
    const int*   pos_inds = (const int*)d_in[4];
    const int*   labels   = (const int*)d_in[5];
    float* out = (float*)d_out;
    float4* partials = (float4*)d_ws;   // 512 * 16 B = 8 KB

    centernet_loss_main<<<NBLOCKS, NTHREADS, 0, stream>>>(
        logits, hms, reg_pred, reg_tgt, pos_inds, labels, partials);
    centernet_loss_reduce<<<1, 256, 0, stream>>>(partials, out);
}